// Round 17
// baseline (304.988 us; speedup 1.0000x reference)
//
#include <hip/hip_runtime.h>
#include <hip/hip_bf16.h>

#define NN0 4096
#define NEDGE 131072
#define NMP 3

typedef __attribute__((ext_vector_type(8))) short bf16x8;
typedef __attribute__((ext_vector_type(4))) float f32x4;

__device__ __forceinline__ unsigned short f2b(float v) {
  __hip_bfloat16 h = __float2bfloat16(v);
  return __builtin_bit_cast(unsigned short, h);
}

__device__ __forceinline__ float b2f(short s) {
  return __builtin_bit_cast(float, ((unsigned)(unsigned short)s) << 16);
}

__device__ __forceinline__ void gload_lds16(const void* g, void* l) {
  __builtin_amdgcn_global_load_lds(
      (const __attribute__((address_space(1))) void*)g,
      (__attribute__((address_space(3))) void*)l, 16, 0, 0);
}

#define MFMA(a, b, c) __builtin_amdgcn_mfma_f32_16x16x32_bf16((a), (b), (c), 0, 0, 0)

// ---------------- fused prep: weight-frag convert + node convert + row histogram ----------------
__device__ __forceinline__ void wfrag_body(const float* __restrict__ src,
                                           unsigned short* __restrict__ dst,
                                           int t, int C, int lgnkt) {
  const int j = t & 7;
  const int l = (t >> 3) & 63;
  const int rest = t >> 9;
  const int kt = rest & ((1 << lgnkt) - 1);
  const int ct = rest >> lgnkt;
  const int r = l & 15, q = l >> 4;
  const int k = (kt << 5) + (q << 3) + j;
  const int c = (ct << 4) + r;
  dst[t] = f2b(src[k * C + c]);
}

__global__ void prep_kernel(
    const float* e1, const float* e2, const float* e3,
    const float* n1, const float* n2, const float* n3, const float* p1,
    unsigned short* We1, unsigned short* We2, unsigned short* We3,
    unsigned short* Wn1, unsigned short* Wn2, unsigned short* Wn3,
    unsigned short* Wp1,
    const float* __restrict__ node0, const float* __restrict__ node1,
    unsigned short* __restrict__ n0b, float* __restrict__ n0f,
    unsigned short* __restrict__ n1b,
    const int* __restrict__ rowi, int* __restrict__ counts) {
  const int b = blockIdx.x;
  const int tid = threadIdx.x;
  if (b < 512)       wfrag_body(e1, We1, (b - 0) * 256 + tid, 256, 4);
  else if (b < 768)  wfrag_body(e2, We2, (b - 512) * 256 + tid, 256, 3);
  else if (b < 1024) wfrag_body(e3, We3, (b - 768) * 256 + tid, 256, 3);
  else if (b < 1536) wfrag_body(n1, Wn1, (b - 1024) * 256 + tid, 256, 4);
  else if (b < 1792) wfrag_body(n2, Wn2, (b - 1536) * 256 + tid, 256, 3);
  else if (b < 2048) wfrag_body(n3, Wn3, (b - 1792) * 256 + tid, 256, 3);
  else if (b < 2560) wfrag_body(p1, Wp1, (b - 2048) * 256 + tid, 256, 4);
  else {
    const int t = (b - 2560) * 256 + tid;
    const float a = node0[t], v = node1[t];
    n0b[t] = f2b(a);
    n0f[t] = a;
    n1b[t] = f2b(v);
    if (t < NEDGE) atomicAdd(&counts[rowi[t]], 1);
  }
}

// ---------------- parallel exclusive scan over 4096 counts ----------------
__global__ void scan_kernel(const int* __restrict__ counts, int* __restrict__ pos) {
  __shared__ int part[256];
  const int t = threadIdx.x;
  const int base = t << 4;
  int local[16];
  int s = 0;
  #pragma unroll
  for (int i = 0; i < 16; ++i) { local[i] = s; s += counts[base + i]; }
  part[t] = s;
  __syncthreads();
  int val = s;
  #pragma unroll
  for (int off = 1; off < 256; off <<= 1) {
    const int add = (t >= off) ? part[t - off] : 0;
    __syncthreads();
    val += add;
    part[t] = val;
    __syncthreads();
  }
  const int excl = val - s;
  #pragma unroll
  for (int i = 0; i < 16; ++i) pos[base + i] = excl + local[i];
}

__global__ void fill_kernel(const int* __restrict__ rowi, int* __restrict__ pos,
                            int* __restrict__ perm) {
  const int e = blockIdx.x * 256 + threadIdx.x;
  if (e < NEDGE) {
    const int slot = atomicAdd(&pos[rowi[e]], 1);
    perm[slot] = e;
  }
}

// ---------------- pre-GEMM: 32-row blocks, 384 blocks ----------------
__global__ __launch_bounds__(256, 2) void pre_gemm_kernel(
    const unsigned short* __restrict__ n0bA, const unsigned short* __restrict__ n1b,
    const unsigned short* __restrict__ We1, const unsigned short* __restrict__ Wp1,
    const float* __restrict__ e_b1,
    unsigned short* __restrict__ P0, unsigned short* __restrict__ P1,
    unsigned short* __restrict__ Pp1)
{
  __shared__ unsigned short smem[32 * 256];    // 16KB
  const int b = blockIdx.x;
  const int grp = b >> 7, mb = b & 127;
  const unsigned short* A;
  const unsigned short* W;
  int ktoff;
  const float* bias;
  unsigned short* out;
  if (grp == 0)      { A = n0bA; W = We1; ktoff = 0; bias = e_b1;    out = P0;  }
  else if (grp == 1) { A = n1b;  W = We1; ktoff = 8; bias = nullptr; out = P1;  }
  else               { A = n1b;  W = Wp1; ktoff = 8; bias = nullptr; out = Pp1; }

  const int tid = (int)threadIdx.x;
  const int ww = tid >> 6, l = tid & 63, r = l & 15, q = l >> 4;
  const int c0 = ww << 6;
  const int swz = (r & 7) << 4;

  #pragma unroll
  for (int s = 0; s < 4; ++s) {
    const int rp = (ww << 3) + (s << 1);
    const int row = rp + (l >> 5);
    const int g = (l & 31) ^ (row & 7);
    gload_lds16(A + (mb * 32 + row) * 256 + g * 8, &smem[rp * 256]);
  }
  __syncthreads();

  f32x4 acc[2][4];
  #pragma unroll
  for (int mt = 0; mt < 2; ++mt)
    #pragma unroll
    for (int nt = 0; nt < 4; ++nt)
      acc[mt][nt] = f32x4{0.f, 0.f, 0.f, 0.f};

  for (int ks = 0; ks < 8; ++ks) {
    bf16x8 a[2];
    #pragma unroll
    for (int mt = 0; mt < 2; ++mt)
      a[mt] = *(const bf16x8*)((const char*)smem + ((mt << 4) + r) * 512 +
                               (((ks << 6) | (q << 4)) ^ swz));
    #pragma unroll
    for (int nt = 0; nt < 4; ++nt) {
      bf16x8 bfr = *(const bf16x8*)(W + ((((ww << 2) + nt) << 4) + ktoff + ks) * 512 + (l << 3));
      #pragma unroll
      for (int mt = 0; mt < 2; ++mt)
        acc[mt][nt] = MFMA(a[mt], bfr, acc[mt][nt]);
    }
  }
  #pragma unroll
  for (int nt = 0; nt < 4; ++nt) {
    const int col = c0 + (nt << 4) + r;
    const float bv = bias ? bias[col] : 0.f;
    #pragma unroll
    for (int mt = 0; mt < 2; ++mt)
      #pragma unroll
      for (int i = 0; i < 4; ++i)
        out[(mb * 32 + (mt << 4) + (q << 2) + i) * 256 + col] = f2b(acc[mt][nt][i] + bv);
  }
}

// ---------------- edge MLP: M=64, 4 waves; in-register reduce; 4 blocks/CU ----------------
// launch_bounds(256,4): kernel fits in 84 VGPR (r16), well under the 128 cap,
// so min-4-waves/EU doubles residency 2->4 blocks/CU without spill risk.
__global__ __launch_bounds__(256, 4) void edge_mlp_kernel(
    const unsigned short* __restrict__ P0b, const unsigned short* __restrict__ P1b,
    const int* __restrict__ rowi, const int* __restrict__ coli,
    const int* __restrict__ perm,
    const unsigned short* __restrict__ W2, const float* __restrict__ b2,
    const float* __restrict__ lng, const float* __restrict__ lnb,
    float* __restrict__ S)
{
  __shared__ unsigned short smem[64 * 256];    // 32KB: H1 (bf16, row-swizzled)
  __shared__ float lnp[512];
  __shared__ int rs_s[64];
  __shared__ unsigned long long bmask_s;

  const int tid = (int)threadIdx.x;
  const int wn = tid >> 6, l = tid & 63, r = l & 15, q = l >> 4;
  const int bid = (int)blockIdx.x;
  const int swzb = ((bid & 7) << 8) + (bid >> 3);   // bijective XCD swizzle (2048 % 8 == 0)
  const int e0 = swzb * 64;
  const int c0 = wn << 6;
  const int swz = (r & 7) << 4;

  const int hrow = tid >> 2;
  const int cq = tid & 3;
  const int pe = perm[e0 + hrow];
  const int mrow = rowi[pe], mcol = coli[pe];
  if (cq == 0) rs_s[hrow] = mrow;
  const unsigned short* pu = P0b + mrow * 256;
  const unsigned short* pv = P1b + mcol * 256;
  const int hswz = (hrow & 7) << 4;

  // H1 = relu(P0[row] + P1[col]) -> LDS (bf16, swizzled)
  #pragma unroll
  for (int jb = 0; jb < 2; ++jb) {
    bf16x8 uu[4], vv[4];
    #pragma unroll
    for (int j = 0; j < 4; ++j) {
      const int col0 = (cq << 6) + (jb << 5) + (j << 3);
      uu[j] = *(const bf16x8*)(pu + col0);
      vv[j] = *(const bf16x8*)(pv + col0);
    }
    #pragma unroll
    for (int j = 0; j < 4; ++j) {
      const int col0 = (cq << 6) + (jb << 5) + (j << 3);
      bf16x8 hpk;
      #pragma unroll
      for (int k = 0; k < 8; ++k)
        hpk[k] = (short)f2b(fmaxf(b2f(uu[j][k]) + b2f(vv[j][k]), 0.f));
      *(bf16x8*)((char*)smem + hrow * 512 + (((unsigned)(col0 * 2)) ^ hswz)) = hpk;
    }
  }
  __syncthreads();                             // barrier 1: H1 + rs_s ready

  if (tid < 64) {
    const bool bnd = (tid == 63) || (rs_s[tid] != rs_s[tid + 1]);
    const unsigned long long m = __ballot(bnd);
    if (tid == 0) bmask_s = m;
  }

  // GEMM2: [64,256] @ [256,256], wave tile 64x64
  f32x4 acc2[4][4];
  #pragma unroll
  for (int mt = 0; mt < 4; ++mt)
    #pragma unroll
    for (int nt = 0; nt < 4; ++nt)
      acc2[mt][nt] = f32x4{0.f, 0.f, 0.f, 0.f};
  __builtin_amdgcn_s_setprio(1);
  for (int ks = 0; ks < 8; ++ks) {
    bf16x8 a[4];
    #pragma unroll
    for (int mt = 0; mt < 4; ++mt)
      a[mt] = *(const bf16x8*)((const char*)smem + ((mt << 4) + r) * 512 +
                               (((ks << 6) | (q << 4)) ^ swz));
    #pragma unroll
    for (int nt = 0; nt < 4; ++nt) {
      bf16x8 b = *(const bf16x8*)(W2 + ((((wn << 2) + nt) << 3) + ks) * 512 + (l << 3));
      #pragma unroll
      for (int mt = 0; mt < 4; ++mt)
        acc2[mt][nt] = MFMA(a[mt], b, acc2[mt][nt]);
    }
  }
  __builtin_amdgcn_s_setprio(0);
  #pragma unroll
  for (int nt = 0; nt < 4; ++nt) {
    const float bias = b2[c0 + (nt << 4) + r];
    #pragma unroll
    for (int mt = 0; mt < 4; ++mt)
      #pragma unroll
      for (int i = 0; i < 4; ++i)
        acc2[mt][nt][i] += bias;
  }
  // LayerNorm stats (per-wave partial over its 64 cols)
  #pragma unroll
  for (int mt = 0; mt < 4; ++mt)
    #pragma unroll
    for (int i = 0; i < 4; ++i) {
      float s = 0.f, s2 = 0.f;
      #pragma unroll
      for (int nt = 0; nt < 4; ++nt) { const float x = acc2[mt][nt][i]; s += x; s2 += x * x; }
      #pragma unroll
      for (int m = 1; m < 16; m <<= 1) { s += __shfl_xor(s, m, 64); s2 += __shfl_xor(s2, m, 64); }
      if (r == 0) {
        const int rr = (mt << 4) + (q << 2) + i;
        lnp[(wn << 6) + rr] = s;
        lnp[256 + (wn << 6) + rr] = s2;
      }
    }
  __syncthreads();                             // barrier 2: lnp + bmask_s visible
  float mu[4][4], rstd[4][4];
  #pragma unroll
  for (int mt = 0; mt < 4; ++mt)
    #pragma unroll
    for (int i = 0; i < 4; ++i) {
      const int rr = (mt << 4) + (q << 2) + i;
      const float s  = lnp[rr] + lnp[64 + rr] + lnp[128 + rr] + lnp[192 + rr];
      const float s2 = lnp[256 + rr] + lnp[256 + 64 + rr] + lnp[256 + 128 + rr] + lnp[256 + 192 + rr];
      const float mean = s * (1.f / 256.f);
      const float var = s2 * (1.f / 256.f) - mean * mean;
      mu[mt][i] = mean;
      rstd[mt][i] = rsqrtf(var + 1e-5f);
    }
  // LN apply + relu IN REGISTERS (no H2 LDS round-trip)
  #pragma unroll
  for (int nt = 0; nt < 4; ++nt) {
    const int hc = c0 + (nt << 4) + r;
    const float gv = lng[hc], bv = lnb[hc];
    #pragma unroll
    for (int mt = 0; mt < 4; ++mt)
      #pragma unroll
      for (int i = 0; i < 4; ++i)
        acc2[mt][nt][i] = fmaxf((acc2[mt][nt][i] - mu[mt][i]) * rstd[mt][i] * gv + bv, 0.f);
  }

  // in-register segmented sums over the 64 sorted edges (wave-uniform segment loop)
  unsigned long long m = bmask_s;
  int a = 0;
  while (m) {
    const int bend = (int)__ffsll((long long)m);     // 1-based lowest set bit = exclusive end
    float sseg[4];
    #pragma unroll
    for (int nt = 0; nt < 4; ++nt) {
      float s = 0.f;
      #pragma unroll
      for (int mt = 0; mt < 4; ++mt)
        #pragma unroll
        for (int i = 0; i < 4; ++i) {
          const int row = (mt << 4) + (q << 2) + i;
          s += (row >= a && row < bend) ? acc2[mt][nt][i] : 0.f;
        }
      s += __shfl_xor(s, 16, 64);
      s += __shfl_xor(s, 32, 64);
      sseg[nt] = s;
    }
    if (q == 0) {
      const int node = rs_s[bend - 1];
      float* dst = S + node * 256 + c0 + r;
      #pragma unroll
      for (int nt = 0; nt < 4; ++nt)
        atomicAdd(dst + (nt << 4), sseg[nt]);
    }
    a = bend;
    m &= (m - 1);
  }
}

// ---------------- node MLP: + fused agg = S@We3 + deg*e_b3 mini-GEMM ----------------
__global__ __launch_bounds__(512, 2) void node_mlp_kernel(
    float* __restrict__ nf, float* __restrict__ S, const int* __restrict__ counts,
    const unsigned short* __restrict__ W1, const float* __restrict__ b1,
    const unsigned short* __restrict__ W2, const float* __restrict__ b2,
    const float* __restrict__ lng, const float* __restrict__ lnb,
    const unsigned short* __restrict__ W3, const float* __restrict__ b3,
    const unsigned short* __restrict__ We3, const float* __restrict__ e_b3,
    const unsigned short* __restrict__ We1, const float* __restrict__ e_b1,
    const unsigned short* __restrict__ Wp1, const float* __restrict__ p_b1,
    unsigned short* __restrict__ P0out, unsigned short* __restrict__ Pp0out)
{
  __shared__ unsigned short smem[16 * 512];
  __shared__ unsigned short Slds[16 * 256];
  __shared__ float lnp[256];
  const int tid = (int)threadIdx.x;
  const int ww = tid >> 6, l = tid & 63, r = l & 15, q = l >> 4;
  const int r0 = (int)blockIdx.x << 4;
  const int c0 = ww << 5;
  const int swz = (r & 7) << 4;

  {
    const int arow = tid >> 5;
    const int kc = tid & 31;
    const int nrow = r0 + arow;
    const int sw = (arow & 7) << 4;
    float v[16];
    if (kc < 16) {
      const float* src = nf + nrow * 256 + (kc << 4);
      *(f32x4*)(v + 0)  = *(const f32x4*)(src + 0);
      *(f32x4*)(v + 4)  = *(const f32x4*)(src + 4);
      *(f32x4*)(v + 8)  = *(const f32x4*)(src + 8);
      *(f32x4*)(v + 12) = *(const f32x4*)(src + 12);
      bf16x8 p0, p1;
      #pragma unroll
      for (int k = 0; k < 8; ++k) { p0[k] = (short)f2b(v[k]); p1[k] = (short)f2b(v[8 + k]); }
      const int base = arow * 1024;
      const int b0 = kc << 5;
      *(bf16x8*)((char*)smem + base + (b0 ^ sw)) = p0;
      *(bf16x8*)((char*)smem + base + ((b0 + 16) ^ sw)) = p1;
    } else {
      const int kc2 = kc - 16;
      float* src = S + nrow * 256 + (kc2 << 4);
      *(f32x4*)(v + 0)  = *(const f32x4*)(src + 0);
      *(f32x4*)(v + 4)  = *(const f32x4*)(src + 4);
      *(f32x4*)(v + 8)  = *(const f32x4*)(src + 8);
      *(f32x4*)(v + 12) = *(const f32x4*)(src + 12);
      *(f32x4*)(src + 0) = f32x4{0.f, 0.f, 0.f, 0.f};
      *(f32x4*)(src + 4) = f32x4{0.f, 0.f, 0.f, 0.f};
      *(f32x4*)(src + 8) = f32x4{0.f, 0.f, 0.f, 0.f};
      *(f32x4*)(src + 12) = f32x4{0.f, 0.f, 0.f, 0.f};
      bf16x8 p0, p1;
      #pragma unroll
      for (int k = 0; k < 8; ++k) { p0[k] = (short)f2b(v[k]); p1[k] = (short)f2b(v[8 + k]); }
      const int base = arow * 512;
      const int b0 = kc2 << 5;
      *(bf16x8*)((char*)Slds + base + (b0 ^ sw)) = p0;
      *(bf16x8*)((char*)Slds + base + ((b0 + 16) ^ sw)) = p1;
    }
  }
  __syncthreads();

  // mini-GEMM: agg16 = Slds @ We3 + deg * e_b3 -> A-tile upper half (bf16)
  {
    f32x4 acc0[2];
    acc0[0] = f32x4{0.f, 0.f, 0.f, 0.f};
    acc0[1] = f32x4{0.f, 0.f, 0.f, 0.f};
    for (int ks = 0; ks < 8; ++ks) {
      bf16x8 a = *(const bf16x8*)((const char*)Slds + r * 512 + (((ks << 6) | (q << 4)) ^ swz));
      #pragma unroll
      for (int nt = 0; nt < 2; ++nt) {
        bf16x8 b = *(const bf16x8*)(We3 + ((((ww << 1) + nt) << 3) + ks) * 512 + (l << 3));
        acc0[nt] = MFMA(a, b, acc0[nt]);
      }
    }
    float degv[4];
    #pragma unroll
    for (int i = 0; i < 4; ++i) degv[i] = (float)counts[r0 + (q << 2) + i];
    #pragma unroll
    for (int nt = 0; nt < 2; ++nt) {
      const int col = c0 + (nt << 4) + r;
      const float bv = e_b3[col];
      #pragma unroll
      for (int i = 0; i < 4; ++i) {
        const int arow = (q << 2) + i;
        const float vv = acc0[nt][i] + degv[i] * bv;
        *(unsigned short*)((char*)smem + arow * 1024 +
                           (((512 + (col << 1))) ^ ((arow & 7) << 4))) = f2b(vv);
      }
    }
  }
  __syncthreads();

  // GEMM1
  f32x4 acc1[2];
  acc1[0] = f32x4{0.f, 0.f, 0.f, 0.f};
  acc1[1] = f32x4{0.f, 0.f, 0.f, 0.f};
  for (int ks = 0; ks < 16; ++ks) {
    bf16x8 a = *(const bf16x8*)((const char*)smem + r * 1024 + (((ks << 6) | (q << 4)) ^ swz));
    #pragma unroll
    for (int nt = 0; nt < 2; ++nt) {
      bf16x8 b = *(const bf16x8*)(W1 + ((((ww << 1) + nt) << 4) + ks) * 512 + (l << 3));
      acc1[nt] = MFMA(a, b, acc1[nt]);
    }
  }
  #pragma unroll
  for (int nt = 0; nt < 2; ++nt) {
    const float bias = b1[c0 + (nt << 4) + r];
    #pragma unroll
    for (int i = 0; i < 4; ++i) acc1[nt][i] = fmaxf(acc1[nt][i] + bias, 0.f);
  }
  __syncthreads();
  #pragma unroll
  for (int i = 0; i < 4; ++i) {
    const int hr = (q << 2) + i;
    const int hswz2 = (hr & 7) << 4;
    #pragma unroll
    for (int nt = 0; nt < 2; ++nt) {
      const int hc = c0 + (nt << 4) + r;
      *(unsigned short*)((char*)smem + hr * 512 + ((hc * 2) ^ hswz2)) = f2b(acc1[nt][i]);
    }
  }
  __syncthreads();

  // GEMM2
  f32x4 acc2[2];
  acc2[0] = f32x4{0.f, 0.f, 0.f, 0.f};
  acc2[1] = f32x4{0.f, 0.f, 0.f, 0.f};
  for (int ks = 0; ks < 8; ++ks) {
    bf16x8 a = *(const bf16x8*)((const char*)smem + r * 512 + (((ks << 6) | (q << 4)) ^ swz));
    #pragma unroll
    for (int nt = 0; nt < 2; ++nt) {
      bf16x8 b = *(const bf16x8*)(W2 + ((((ww << 1) + nt) << 3) + ks) * 512 + (l << 3));
      acc2[nt] = MFMA(a, b, acc2[nt]);
    }
  }
  #pragma unroll
  for (int nt = 0; nt < 2; ++nt) {
    const float bias = b2[c0 + (nt << 4) + r];
    #pragma unroll
    for (int i = 0; i < 4; ++i) acc2[nt][i] += bias;
  }
  #pragma unroll
  for (int i = 0; i < 4; ++i) {
    float s = acc2[0][i] + acc2[1][i];
    float s2 = acc2[0][i] * acc2[0][i] + acc2[1][i] * acc2[1][i];
    #pragma unroll
    for (int m = 1; m < 16; m <<= 1) { s += __shfl_xor(s, m, 64); s2 += __shfl_xor(s2, m, 64); }
    if (r == 0) {
      const int rr = (q << 2) + i;
      lnp[ww * 16 + rr] = s;
      lnp[128 + ww * 16 + rr] = s2;
    }
  }
  __syncthreads();
  float mu[4], rstd[4];
  #pragma unroll
  for (int i = 0; i < 4; ++i) {
    const int rr = (q << 2) + i;
    float s = 0.f, s2 = 0.f;
    #pragma unroll
    for (int w2i = 0; w2i < 8; ++w2i) { s += lnp[w2i * 16 + rr]; s2 += lnp[128 + w2i * 16 + rr]; }
    const float mean = s * (1.f / 256.f);
    const float var = s2 * (1.f / 256.f) - mean * mean;
    mu[i] = mean;
    rstd[i] = rsqrtf(var + 1e-5f);
  }
  #pragma unroll
  for (int nt = 0; nt < 2; ++nt) {
    const int hc = c0 + (nt << 4) + r;
    const float gv = lng[hc], bv = lnb[hc];
    #pragma unroll
    for (int i = 0; i < 4; ++i) {
      const int hr = (q << 2) + i;
      const float x = fmaxf((acc2[nt][i] - mu[i]) * rstd[i] * gv + bv, 0.f);
      *(unsigned short*)((char*)smem + hr * 512 + ((hc * 2) ^ ((hr & 7) << 4))) = f2b(x);
    }
  }
  __syncthreads();

  // GEMM3 + residual
  f32x4 acc3[2];
  acc3[0] = f32x4{0.f, 0.f, 0.f, 0.f};
  acc3[1] = f32x4{0.f, 0.f, 0.f, 0.f};
  for (int ks = 0; ks < 8; ++ks) {
    bf16x8 a = *(const bf16x8*)((const char*)smem + r * 512 + (((ks << 6) | (q << 4)) ^ swz));
    #pragma unroll
    for (int nt = 0; nt < 2; ++nt) {
      bf16x8 b = *(const bf16x8*)(W3 + ((((ww << 1) + nt) << 3) + ks) * 512 + (l << 3));
      acc3[nt] = MFMA(a, b, acc3[nt]);
    }
  }
  float y_loc[4][2];
  #pragma unroll
  for (int nt = 0; nt < 2; ++nt) {
    const float bias3 = b3[c0 + (nt << 4) + r];
    #pragma unroll
    for (int i = 0; i < 4; ++i) {
      const int nrow = r0 + (q << 2) + i;
      const int col = c0 + (nt << 4) + r;
      const float y = acc3[nt][i] + bias3 + nf[nrow * 256 + col];
      nf[nrow * 256 + col] = y;
      y_loc[i][nt] = y;
    }
  }
  __syncthreads();
  #pragma unroll
  for (int i = 0; i < 4; ++i) {
    const int hr = (q << 2) + i;
    const int hswz2 = (hr & 7) << 4;
    #pragma unroll
    for (int nt = 0; nt < 2; ++nt) {
      const int hc = c0 + (nt << 4) + r;
      *(unsigned short*)((char*)smem + hr * 512 + ((hc * 2) ^ hswz2)) = f2b(y_loc[i][nt]);
    }
  }
  __syncthreads();

  // P0 = y @ We1_top + e_b1
  f32x4 acc4[2];
  acc4[0] = f32x4{0.f, 0.f, 0.f, 0.f};
  acc4[1] = f32x4{0.f, 0.f, 0.f, 0.f};
  for (int ks = 0; ks < 8; ++ks) {
    bf16x8 a = *(const bf16x8*)((const char*)smem + r * 512 + (((ks << 6) | (q << 4)) ^ swz));
    #pragma unroll
    for (int nt = 0; nt < 2; ++nt) {
      bf16x8 b = *(const bf16x8*)(We1 + ((((ww << 1) + nt) << 4) + ks) * 512 + (l << 3));
      acc4[nt] = MFMA(a, b, acc4[nt]);
    }
  }
  #pragma unroll
  for (int nt = 0; nt < 2; ++nt) {
    const int col = c0 + (nt << 4) + r;
    const float bv = e_b1[col];
    #pragma unroll
    for (int i = 0; i < 4; ++i)
      P0out[(r0 + (q << 2) + i) * 256 + col] = f2b(acc4[nt][i] + bv);
  }

  if (Pp0out != nullptr) {
    f32x4 acc5[2];
    acc5[0] = f32x4{0.f, 0.f, 0.f, 0.f};
    acc5[1] = f32x4{0.f, 0.f, 0.f, 0.f};
    for (int ks = 0; ks < 8; ++ks) {
      bf16x8 a = *(const bf16x8*)((const char*)smem + r * 512 + (((ks << 6) | (q << 4)) ^ swz));
      #pragma unroll
      for (int nt = 0; nt < 2; ++nt) {
        bf16x8 b = *(const bf16x8*)(Wp1 + ((((ww << 1) + nt) << 4) + ks) * 512 + (l << 3));
        acc5[nt] = MFMA(a, b, acc5[nt]);
      }
    }
    #pragma unroll
    for (int nt = 0; nt < 2; ++nt) {
      const int col = c0 + (nt << 4) + r;
      const float bv = p_b1[col];
      #pragma unroll
      for (int i = 0; i < 4; ++i)
        Pp0out[(r0 + (q << 2) + i) * 256 + col] = f2b(acc5[nt][i] + bv);
    }
  }
}

// ---------------- edge predictor: sorted-order gather+add+relu+dot+sigmoid ----------------
__global__ __launch_bounds__(256, 4) void pred_kernel(
    const unsigned short* __restrict__ Pp0, const unsigned short* __restrict__ Pp1,
    const int* __restrict__ rowi, const int* __restrict__ coli,
    const int* __restrict__ perm,
    const float* __restrict__ w2, const float* __restrict__ b2,
    float* __restrict__ out)
{
  const int g = (int)blockIdx.x * 256 + (int)threadIdx.x;
  const int e = perm[g];
  const int prow = rowi[e] * 256, pcol = coli[e] * 256;
  float acc = 0.f;
  #pragma unroll 4
  for (int j = 0; j < 32; ++j) {
    const bf16x8 u = *(const bf16x8*)(Pp0 + prow + (j << 3));
    const bf16x8 v = *(const bf16x8*)(Pp1 + pcol + (j << 3));
    #pragma unroll
    for (int k = 0; k < 8; ++k)
      acc += fmaxf(b2f(u[k]) + b2f(v[k]), 0.f) * w2[(j << 3) + k];
  }
  out[e] = 1.f / (1.f + expf(-(acc + b2[0])));
}

// ---------------- launch ----------------
extern "C" void kernel_launch(void* const* d_in, const int* in_sizes, int n_in,
                              void* d_out, int out_size, void* d_ws, size_t ws_size,
                              hipStream_t stream) {
  const float* node0 = (const float*)d_in[0];
  const float* node1 = (const float*)d_in[1];
  const int* rowi = (const int*)d_in[2];
  const int* coli = (const int*)d_in[3];
  const float* e_w1 = (const float*)d_in[4];
  const float* e_b1 = (const float*)d_in[5];
  const float* e_w2 = (const float*)d_in[6];
  const float* e_b2 = (const float*)d_in[7];
  const float* e_g  = (const float*)d_in[8];
  const float* e_be = (const float*)d_in[9];
  const float* e_w3 = (const float*)d_in[10];
  const float* e_b3 = (const float*)d_in[11];
  const float* n_w1 = (const float*)d_in[12];
  const float* n_b1 = (const float*)d_in[13];
  const float* n_w2 = (const float*)d_in[14];
  const float* n_b2 = (const float*)d_in[15];
  const float* n_g  = (const float*)d_in[16];
  const float* n_be = (const float*)d_in[17];
  const float* n_w3 = (const float*)d_in[18];
  const float* n_b3 = (const float*)d_in[19];
  const float* p_w1 = (const float*)d_in[20];
  const float* p_b1 = (const float*)d_in[21];
  const float* p_w2 = (const float*)d_in[22];
  const float* p_b2 = (const float*)d_in[23];

  char* ws = (char*)d_ws;
  unsigned short* WTe1 = (unsigned short*)(ws + 0);
  unsigned short* WTe2 = (unsigned short*)(ws + 262144);
  unsigned short* WTe3 = (unsigned short*)(ws + 393216);
  unsigned short* WTn1 = (unsigned short*)(ws + 524288);
  unsigned short* WTn2 = (unsigned short*)(ws + 786432);
  unsigned short* WTn3 = (unsigned short*)(ws + 917504);
  unsigned short* WTp1 = (unsigned short*)(ws + 1048576);
  unsigned short* n1b  = (unsigned short*)(ws + 1310720);
  unsigned short* n0b  = (unsigned short*)(ws + 3407872);
  unsigned short* P0b  = (unsigned short*)(ws + 5505024);
  unsigned short* P1b  = (unsigned short*)(ws + 7602176);
  unsigned short* Pp0b = (unsigned short*)(ws + 9699328);
  unsigned short* Pp1b = (unsigned short*)(ws + 11796480);
  float* n0f  = (float*)(ws + 13893632);
  float* agg  = (float*)(ws + 18087936);     // S: segment sums of H2
  int* perm   = (int*)(ws + 22282240);
  int* posb   = (int*)(ws + 22806528);
  int* counts = (int*)(ws + 22822912);

  hipMemsetAsync(counts, 0, 4096 * 4, stream);
  hipMemsetAsync(agg, 0, (size_t)NN0 * 256 * 4, stream);
  prep_kernel<<<6656, 256, 0, stream>>>(e_w1, e_w2, e_w3, n_w1, n_w2, n_w3, p_w1,
                                        WTe1, WTe2, WTe3, WTn1, WTn2, WTn3, WTp1,
                                        node0, node1, n0b, n0f, n1b, rowi, counts);
  scan_kernel<<<1, 256, 0, stream>>>(counts, posb);
  fill_kernel<<<512, 256, 0, stream>>>(rowi, posb, perm);

  pre_gemm_kernel<<<384, 256, 0, stream>>>(n0b, n1b, WTe1, WTp1, e_b1, P0b, P1b, Pp1b);

  for (int it = 0; it < NMP; ++it) {
    edge_mlp_kernel<<<NEDGE / 64, 256, 0, stream>>>(P0b, P1b, rowi, coli, perm,
        WTe2, e_b2, e_g, e_be, agg);
    node_mlp_kernel<<<NN0 / 16, 512, 0, stream>>>(n0f, agg, counts,
        WTn1, n_b1, WTn2, n_b2, n_g, n_be, WTn3, n_b3,
        WTe3, e_b3, WTe1, e_b1, WTp1, p_b1, P0b, (it == NMP - 1) ? Pp0b : nullptr);
  }
  pred_kernel<<<NEDGE / 256, 256, 0, stream>>>(Pp0b, Pp1b, rowi, coli, perm,
      p_w2, p_b2, (float*)d_out);
}

// Round 18
// 279.634 us; speedup vs baseline: 1.0907x; 1.0907x over previous
//
#include <hip/hip_runtime.h>
#include <hip/hip_bf16.h>

#define NN0 4096
#define NEDGE 131072
#define NMP 3

typedef __attribute__((ext_vector_type(8))) short bf16x8;
typedef __attribute__((ext_vector_type(4))) float f32x4;

__device__ __forceinline__ unsigned short f2b(float v) {
  __hip_bfloat16 h = __float2bfloat16(v);
  return __builtin_bit_cast(unsigned short, h);
}

__device__ __forceinline__ float b2f(short s) {
  return __builtin_bit_cast(float, ((unsigned)(unsigned short)s) << 16);
}

__device__ __forceinline__ void gload_lds16(const void* g, void* l) {
  __builtin_amdgcn_global_load_lds(
      (const __attribute__((address_space(1))) void*)g,
      (__attribute__((address_space(3))) void*)l, 16, 0, 0);
}

#define MFMA(a, b, c) __builtin_amdgcn_mfma_f32_16x16x32_bf16((a), (b), (c), 0, 0, 0)

// ---------------- fused prep: weight-frag convert + node convert + row histogram ----------------
__device__ __forceinline__ void wfrag_body(const float* __restrict__ src,
                                           unsigned short* __restrict__ dst,
                                           int t, int C, int lgnkt) {
  const int j = t & 7;
  const int l = (t >> 3) & 63;
  const int rest = t >> 9;
  const int kt = rest & ((1 << lgnkt) - 1);
  const int ct = rest >> lgnkt;
  const int r = l & 15, q = l >> 4;
  const int k = (kt << 5) + (q << 3) + j;
  const int c = (ct << 4) + r;
  dst[t] = f2b(src[k * C + c]);
}

__global__ void prep_kernel(
    const float* e1, const float* e2, const float* e3,
    const float* n1, const float* n2, const float* n3, const float* p1,
    unsigned short* We1, unsigned short* We2, unsigned short* We3,
    unsigned short* Wn1, unsigned short* Wn2, unsigned short* Wn3,
    unsigned short* Wp1,
    const float* __restrict__ node0, const float* __restrict__ node1,
    unsigned short* __restrict__ n0b, float* __restrict__ n0f,
    unsigned short* __restrict__ n1b,
    const int* __restrict__ rowi, int* __restrict__ counts) {
  const int b = blockIdx.x;
  const int tid = threadIdx.x;
  if (b < 512)       wfrag_body(e1, We1, (b - 0) * 256 + tid, 256, 4);
  else if (b < 768)  wfrag_body(e2, We2, (b - 512) * 256 + tid, 256, 3);
  else if (b < 1024) wfrag_body(e3, We3, (b - 768) * 256 + tid, 256, 3);
  else if (b < 1536) wfrag_body(n1, Wn1, (b - 1024) * 256 + tid, 256, 4);
  else if (b < 1792) wfrag_body(n2, Wn2, (b - 1536) * 256 + tid, 256, 3);
  else if (b < 2048) wfrag_body(n3, Wn3, (b - 1792) * 256 + tid, 256, 3);
  else if (b < 2560) wfrag_body(p1, Wp1, (b - 2048) * 256 + tid, 256, 4);
  else {
    const int t = (b - 2560) * 256 + tid;
    const float a = node0[t], v = node1[t];
    n0b[t] = f2b(a);
    n0f[t] = a;
    n1b[t] = f2b(v);
    if (t < NEDGE) atomicAdd(&counts[rowi[t]], 1);
  }
}

// ---------------- parallel exclusive scan over 4096 counts ----------------
__global__ void scan_kernel(const int* __restrict__ counts, int* __restrict__ pos) {
  __shared__ int part[256];
  const int t = threadIdx.x;
  const int base = t << 4;
  int local[16];
  int s = 0;
  #pragma unroll
  for (int i = 0; i < 16; ++i) { local[i] = s; s += counts[base + i]; }
  part[t] = s;
  __syncthreads();
  int val = s;
  #pragma unroll
  for (int off = 1; off < 256; off <<= 1) {
    const int add = (t >= off) ? part[t - off] : 0;
    __syncthreads();
    val += add;
    part[t] = val;
    __syncthreads();
  }
  const int excl = val - s;
  #pragma unroll
  for (int i = 0; i < 16; ++i) pos[base + i] = excl + local[i];
}

__global__ void fill_kernel(const int* __restrict__ rowi, int* __restrict__ pos,
                            int* __restrict__ perm) {
  const int e = blockIdx.x * 256 + threadIdx.x;
  if (e < NEDGE) {
    const int slot = atomicAdd(&pos[rowi[e]], 1);
    perm[slot] = e;
  }
}

// ---------------- pre-GEMM: 32-row blocks, 384 blocks ----------------
__global__ __launch_bounds__(256, 2) void pre_gemm_kernel(
    const unsigned short* __restrict__ n0bA, const unsigned short* __restrict__ n1b,
    const unsigned short* __restrict__ We1, const unsigned short* __restrict__ Wp1,
    const float* __restrict__ e_b1,
    unsigned short* __restrict__ P0, unsigned short* __restrict__ P1,
    unsigned short* __restrict__ Pp1)
{
  __shared__ unsigned short smem[32 * 256];    // 16KB
  const int b = blockIdx.x;
  const int grp = b >> 7, mb = b & 127;
  const unsigned short* A;
  const unsigned short* W;
  int ktoff;
  const float* bias;
  unsigned short* out;
  if (grp == 0)      { A = n0bA; W = We1; ktoff = 0; bias = e_b1;    out = P0;  }
  else if (grp == 1) { A = n1b;  W = We1; ktoff = 8; bias = nullptr; out = P1;  }
  else               { A = n1b;  W = Wp1; ktoff = 8; bias = nullptr; out = Pp1; }

  const int tid = (int)threadIdx.x;
  const int ww = tid >> 6, l = tid & 63, r = l & 15, q = l >> 4;
  const int c0 = ww << 6;
  const int swz = (r & 7) << 4;

  #pragma unroll
  for (int s = 0; s < 4; ++s) {
    const int rp = (ww << 3) + (s << 1);
    const int row = rp + (l >> 5);
    const int g = (l & 31) ^ (row & 7);
    gload_lds16(A + (mb * 32 + row) * 256 + g * 8, &smem[rp * 256]);
  }
  __syncthreads();

  f32x4 acc[2][4];
  #pragma unroll
  for (int mt = 0; mt < 2; ++mt)
    #pragma unroll
    for (int nt = 0; nt < 4; ++nt)
      acc[mt][nt] = f32x4{0.f, 0.f, 0.f, 0.f};

  for (int ks = 0; ks < 8; ++ks) {
    bf16x8 a[2];
    #pragma unroll
    for (int mt = 0; mt < 2; ++mt)
      a[mt] = *(const bf16x8*)((const char*)smem + ((mt << 4) + r) * 512 +
                               (((ks << 6) | (q << 4)) ^ swz));
    #pragma unroll
    for (int nt = 0; nt < 4; ++nt) {
      bf16x8 bfr = *(const bf16x8*)(W + ((((ww << 2) + nt) << 4) + ktoff + ks) * 512 + (l << 3));
      #pragma unroll
      for (int mt = 0; mt < 2; ++mt)
        acc[mt][nt] = MFMA(a[mt], bfr, acc[mt][nt]);
    }
  }
  #pragma unroll
  for (int nt = 0; nt < 4; ++nt) {
    const int col = c0 + (nt << 4) + r;
    const float bv = bias ? bias[col] : 0.f;
    #pragma unroll
    for (int mt = 0; mt < 2; ++mt)
      #pragma unroll
      for (int i = 0; i < 4; ++i)
        out[(mb * 32 + (mt << 4) + (q << 2) + i) * 256 + col] = f2b(acc[mt][nt][i] + bv);
  }
}

// ---------------- edge MLP: M=64, 4 waves; in-register reduce ----------------
// launch_bounds(256,3): VGPR cap ~170 >> natural need (~84) so no tier-snap spill
// (r17 lesson: (256,4)'s cap 128 made the allocator snap to 64 + spill).
__global__ __launch_bounds__(256, 3) void edge_mlp_kernel(
    const unsigned short* __restrict__ P0b, const unsigned short* __restrict__ P1b,
    const int* __restrict__ rowi, const int* __restrict__ coli,
    const int* __restrict__ perm,
    const unsigned short* __restrict__ W2, const float* __restrict__ b2,
    const float* __restrict__ lng, const float* __restrict__ lnb,
    float* __restrict__ S)
{
  __shared__ unsigned short smem[64 * 256];    // 32KB: H1 (bf16, row-swizzled)
  __shared__ float lnp[512];
  __shared__ int rs_s[64];
  __shared__ unsigned long long bmask_s;

  const int tid = (int)threadIdx.x;
  const int wn = tid >> 6, l = tid & 63, r = l & 15, q = l >> 4;
  const int bid = (int)blockIdx.x;
  const int swzb = ((bid & 7) << 8) + (bid >> 3);   // bijective XCD swizzle (2048 % 8 == 0)
  const int e0 = swzb * 64;
  const int c0 = wn << 6;
  const int swz = (r & 7) << 4;

  const int hrow = tid >> 2;
  const int cq = tid & 3;
  const int pe = perm[e0 + hrow];
  const int mrow = rowi[pe], mcol = coli[pe];
  if (cq == 0) rs_s[hrow] = mrow;
  const unsigned short* pu = P0b + mrow * 256;
  const unsigned short* pv = P1b + mcol * 256;
  const int hswz = (hrow & 7) << 4;

  // H1 = relu(P0[row] + P1[col]) -> LDS (bf16, swizzled)
  #pragma unroll
  for (int jb = 0; jb < 2; ++jb) {
    bf16x8 uu[4], vv[4];
    #pragma unroll
    for (int j = 0; j < 4; ++j) {
      const int col0 = (cq << 6) + (jb << 5) + (j << 3);
      uu[j] = *(const bf16x8*)(pu + col0);
      vv[j] = *(const bf16x8*)(pv + col0);
    }
    #pragma unroll
    for (int j = 0; j < 4; ++j) {
      const int col0 = (cq << 6) + (jb << 5) + (j << 3);
      bf16x8 hpk;
      #pragma unroll
      for (int k = 0; k < 8; ++k)
        hpk[k] = (short)f2b(fmaxf(b2f(uu[j][k]) + b2f(vv[j][k]), 0.f));
      *(bf16x8*)((char*)smem + hrow * 512 + (((unsigned)(col0 * 2)) ^ hswz)) = hpk;
    }
  }
  __syncthreads();                             // barrier 1: H1 + rs_s ready

  if (tid < 64) {
    const bool bnd = (tid == 63) || (rs_s[tid] != rs_s[tid + 1]);
    const unsigned long long m = __ballot(bnd);
    if (tid == 0) bmask_s = m;
  }

  // GEMM2: [64,256] @ [256,256], wave tile 64x64
  f32x4 acc2[4][4];
  #pragma unroll
  for (int mt = 0; mt < 4; ++mt)
    #pragma unroll
    for (int nt = 0; nt < 4; ++nt)
      acc2[mt][nt] = f32x4{0.f, 0.f, 0.f, 0.f};
  __builtin_amdgcn_s_setprio(1);
  for (int ks = 0; ks < 8; ++ks) {
    bf16x8 a[4];
    #pragma unroll
    for (int mt = 0; mt < 4; ++mt)
      a[mt] = *(const bf16x8*)((const char*)smem + ((mt << 4) + r) * 512 +
                               (((ks << 6) | (q << 4)) ^ swz));
    #pragma unroll
    for (int nt = 0; nt < 4; ++nt) {
      bf16x8 b = *(const bf16x8*)(W2 + ((((wn << 2) + nt) << 3) + ks) * 512 + (l << 3));
      #pragma unroll
      for (int mt = 0; mt < 4; ++mt)
        acc2[mt][nt] = MFMA(a[mt], b, acc2[mt][nt]);
    }
  }
  __builtin_amdgcn_s_setprio(0);
  #pragma unroll
  for (int nt = 0; nt < 4; ++nt) {
    const float bias = b2[c0 + (nt << 4) + r];
    #pragma unroll
    for (int mt = 0; mt < 4; ++mt)
      #pragma unroll
      for (int i = 0; i < 4; ++i)
        acc2[mt][nt][i] += bias;
  }
  // LayerNorm stats (per-wave partial over its 64 cols)
  #pragma unroll
  for (int mt = 0; mt < 4; ++mt)
    #pragma unroll
    for (int i = 0; i < 4; ++i) {
      float s = 0.f, s2 = 0.f;
      #pragma unroll
      for (int nt = 0; nt < 4; ++nt) { const float x = acc2[mt][nt][i]; s += x; s2 += x * x; }
      #pragma unroll
      for (int m = 1; m < 16; m <<= 1) { s += __shfl_xor(s, m, 64); s2 += __shfl_xor(s2, m, 64); }
      if (r == 0) {
        const int rr = (mt << 4) + (q << 2) + i;
        lnp[(wn << 6) + rr] = s;
        lnp[256 + (wn << 6) + rr] = s2;
      }
    }
  __syncthreads();                             // barrier 2: lnp + bmask_s visible
  float mu[4][4], rstd[4][4];
  #pragma unroll
  for (int mt = 0; mt < 4; ++mt)
    #pragma unroll
    for (int i = 0; i < 4; ++i) {
      const int rr = (mt << 4) + (q << 2) + i;
      const float s  = lnp[rr] + lnp[64 + rr] + lnp[128 + rr] + lnp[192 + rr];
      const float s2 = lnp[256 + rr] + lnp[256 + 64 + rr] + lnp[256 + 128 + rr] + lnp[256 + 192 + rr];
      const float mean = s * (1.f / 256.f);
      const float var = s2 * (1.f / 256.f) - mean * mean;
      mu[mt][i] = mean;
      rstd[mt][i] = rsqrtf(var + 1e-5f);
    }
  // LN apply + relu IN REGISTERS (no H2 LDS round-trip)
  #pragma unroll
  for (int nt = 0; nt < 4; ++nt) {
    const int hc = c0 + (nt << 4) + r;
    const float gv = lng[hc], bv = lnb[hc];
    #pragma unroll
    for (int mt = 0; mt < 4; ++mt)
      #pragma unroll
      for (int i = 0; i < 4; ++i)
        acc2[mt][nt][i] = fmaxf((acc2[mt][nt][i] - mu[mt][i]) * rstd[mt][i] * gv + bv, 0.f);
  }

  // in-register segmented sums over the 64 sorted edges (wave-uniform segment loop)
  unsigned long long m = bmask_s;
  int a = 0;
  while (m) {
    const int bend = (int)__ffsll((long long)m);     // 1-based lowest set bit = exclusive end
    float sseg[4];
    #pragma unroll
    for (int nt = 0; nt < 4; ++nt) {
      float s = 0.f;
      #pragma unroll
      for (int mt = 0; mt < 4; ++mt)
        #pragma unroll
        for (int i = 0; i < 4; ++i) {
          const int row = (mt << 4) + (q << 2) + i;
          s += (row >= a && row < bend) ? acc2[mt][nt][i] : 0.f;
        }
      s += __shfl_xor(s, 16, 64);
      s += __shfl_xor(s, 32, 64);
      sseg[nt] = s;
    }
    if (q == 0) {
      const int node = rs_s[bend - 1];
      float* dst = S + node * 256 + c0 + r;
      #pragma unroll
      for (int nt = 0; nt < 4; ++nt)
        atomicAdd(dst + (nt << 4), sseg[nt]);
    }
    a = bend;
    m &= (m - 1);
  }
}

// ---------------- node MLP: + fused agg = S@We3 + deg*e_b3 mini-GEMM ----------------
__global__ __launch_bounds__(512, 2) void node_mlp_kernel(
    float* __restrict__ nf, float* __restrict__ S, const int* __restrict__ counts,
    const unsigned short* __restrict__ W1, const float* __restrict__ b1,
    const unsigned short* __restrict__ W2, const float* __restrict__ b2,
    const float* __restrict__ lng, const float* __restrict__ lnb,
    const unsigned short* __restrict__ W3, const float* __restrict__ b3,
    const unsigned short* __restrict__ We3, const float* __restrict__ e_b3,
    const unsigned short* __restrict__ We1, const float* __restrict__ e_b1,
    const unsigned short* __restrict__ Wp1, const float* __restrict__ p_b1,
    unsigned short* __restrict__ P0out, unsigned short* __restrict__ Pp0out)
{
  __shared__ unsigned short smem[16 * 512];
  __shared__ unsigned short Slds[16 * 256];
  __shared__ float lnp[256];
  const int tid = (int)threadIdx.x;
  const int ww = tid >> 6, l = tid & 63, r = l & 15, q = l >> 4;
  const int r0 = (int)blockIdx.x << 4;
  const int c0 = ww << 5;
  const int swz = (r & 7) << 4;

  {
    const int arow = tid >> 5;
    const int kc = tid & 31;
    const int nrow = r0 + arow;
    const int sw = (arow & 7) << 4;
    float v[16];
    if (kc < 16) {
      const float* src = nf + nrow * 256 + (kc << 4);
      *(f32x4*)(v + 0)  = *(const f32x4*)(src + 0);
      *(f32x4*)(v + 4)  = *(const f32x4*)(src + 4);
      *(f32x4*)(v + 8)  = *(const f32x4*)(src + 8);
      *(f32x4*)(v + 12) = *(const f32x4*)(src + 12);
      bf16x8 p0, p1;
      #pragma unroll
      for (int k = 0; k < 8; ++k) { p0[k] = (short)f2b(v[k]); p1[k] = (short)f2b(v[8 + k]); }
      const int base = arow * 1024;
      const int b0 = kc << 5;
      *(bf16x8*)((char*)smem + base + (b0 ^ sw)) = p0;
      *(bf16x8*)((char*)smem + base + ((b0 + 16) ^ sw)) = p1;
    } else {
      const int kc2 = kc - 16;
      float* src = S + nrow * 256 + (kc2 << 4);
      *(f32x4*)(v + 0)  = *(const f32x4*)(src + 0);
      *(f32x4*)(v + 4)  = *(const f32x4*)(src + 4);
      *(f32x4*)(v + 8)  = *(const f32x4*)(src + 8);
      *(f32x4*)(v + 12) = *(const f32x4*)(src + 12);
      *(f32x4*)(src + 0) = f32x4{0.f, 0.f, 0.f, 0.f};
      *(f32x4*)(src + 4) = f32x4{0.f, 0.f, 0.f, 0.f};
      *(f32x4*)(src + 8) = f32x4{0.f, 0.f, 0.f, 0.f};
      *(f32x4*)(src + 12) = f32x4{0.f, 0.f, 0.f, 0.f};
      bf16x8 p0, p1;
      #pragma unroll
      for (int k = 0; k < 8; ++k) { p0[k] = (short)f2b(v[k]); p1[k] = (short)f2b(v[8 + k]); }
      const int base = arow * 512;
      const int b0 = kc2 << 5;
      *(bf16x8*)((char*)Slds + base + (b0 ^ sw)) = p0;
      *(bf16x8*)((char*)Slds + base + ((b0 + 16) ^ sw)) = p1;
    }
  }
  __syncthreads();

  // mini-GEMM: agg16 = Slds @ We3 + deg * e_b3 -> A-tile upper half (bf16)
  {
    f32x4 acc0[2];
    acc0[0] = f32x4{0.f, 0.f, 0.f, 0.f};
    acc0[1] = f32x4{0.f, 0.f, 0.f, 0.f};
    for (int ks = 0; ks < 8; ++ks) {
      bf16x8 a = *(const bf16x8*)((const char*)Slds + r * 512 + (((ks << 6) | (q << 4)) ^ swz));
      #pragma unroll
      for (int nt = 0; nt < 2; ++nt) {
        bf16x8 b = *(const bf16x8*)(We3 + ((((ww << 1) + nt) << 3) + ks) * 512 + (l << 3));
        acc0[nt] = MFMA(a, b, acc0[nt]);
      }
    }
    float degv[4];
    #pragma unroll
    for (int i = 0; i < 4; ++i) degv[i] = (float)counts[r0 + (q << 2) + i];
    #pragma unroll
    for (int nt = 0; nt < 2; ++nt) {
      const int col = c0 + (nt << 4) + r;
      const float bv = e_b3[col];
      #pragma unroll
      for (int i = 0; i < 4; ++i) {
        const int arow = (q << 2) + i;
        const float vv = acc0[nt][i] + degv[i] * bv;
        *(unsigned short*)((char*)smem + arow * 1024 +
                           (((512 + (col << 1))) ^ ((arow & 7) << 4))) = f2b(vv);
      }
    }
  }
  __syncthreads();

  // GEMM1
  f32x4 acc1[2];
  acc1[0] = f32x4{0.f, 0.f, 0.f, 0.f};
  acc1[1] = f32x4{0.f, 0.f, 0.f, 0.f};
  for (int ks = 0; ks < 16; ++ks) {
    bf16x8 a = *(const bf16x8*)((const char*)smem + r * 1024 + (((ks << 6) | (q << 4)) ^ swz));
    #pragma unroll
    for (int nt = 0; nt < 2; ++nt) {
      bf16x8 b = *(const bf16x8*)(W1 + ((((ww << 1) + nt) << 4) + ks) * 512 + (l << 3));
      acc1[nt] = MFMA(a, b, acc1[nt]);
    }
  }
  #pragma unroll
  for (int nt = 0; nt < 2; ++nt) {
    const float bias = b1[c0 + (nt << 4) + r];
    #pragma unroll
    for (int i = 0; i < 4; ++i) acc1[nt][i] = fmaxf(acc1[nt][i] + bias, 0.f);
  }
  __syncthreads();
  #pragma unroll
  for (int i = 0; i < 4; ++i) {
    const int hr = (q << 2) + i;
    const int hswz2 = (hr & 7) << 4;
    #pragma unroll
    for (int nt = 0; nt < 2; ++nt) {
      const int hc = c0 + (nt << 4) + r;
      *(unsigned short*)((char*)smem + hr * 512 + ((hc * 2) ^ hswz2)) = f2b(acc1[nt][i]);
    }
  }
  __syncthreads();

  // GEMM2
  f32x4 acc2[2];
  acc2[0] = f32x4{0.f, 0.f, 0.f, 0.f};
  acc2[1] = f32x4{0.f, 0.f, 0.f, 0.f};
  for (int ks = 0; ks < 8; ++ks) {
    bf16x8 a = *(const bf16x8*)((const char*)smem + r * 512 + (((ks << 6) | (q << 4)) ^ swz));
    #pragma unroll
    for (int nt = 0; nt < 2; ++nt) {
      bf16x8 b = *(const bf16x8*)(W2 + ((((ww << 1) + nt) << 3) + ks) * 512 + (l << 3));
      acc2[nt] = MFMA(a, b, acc2[nt]);
    }
  }
  #pragma unroll
  for (int nt = 0; nt < 2; ++nt) {
    const float bias = b2[c0 + (nt << 4) + r];
    #pragma unroll
    for (int i = 0; i < 4; ++i) acc2[nt][i] += bias;
  }
  #pragma unroll
  for (int i = 0; i < 4; ++i) {
    float s = acc2[0][i] + acc2[1][i];
    float s2 = acc2[0][i] * acc2[0][i] + acc2[1][i] * acc2[1][i];
    #pragma unroll
    for (int m = 1; m < 16; m <<= 1) { s += __shfl_xor(s, m, 64); s2 += __shfl_xor(s2, m, 64); }
    if (r == 0) {
      const int rr = (q << 2) + i;
      lnp[ww * 16 + rr] = s;
      lnp[128 + ww * 16 + rr] = s2;
    }
  }
  __syncthreads();
  float mu[4], rstd[4];
  #pragma unroll
  for (int i = 0; i < 4; ++i) {
    const int rr = (q << 2) + i;
    float s = 0.f, s2 = 0.f;
    #pragma unroll
    for (int w2i = 0; w2i < 8; ++w2i) { s += lnp[w2i * 16 + rr]; s2 += lnp[128 + w2i * 16 + rr]; }
    const float mean = s * (1.f / 256.f);
    const float var = s2 * (1.f / 256.f) - mean * mean;
    mu[i] = mean;
    rstd[i] = rsqrtf(var + 1e-5f);
  }
  #pragma unroll
  for (int nt = 0; nt < 2; ++nt) {
    const int hc = c0 + (nt << 4) + r;
    const float gv = lng[hc], bv = lnb[hc];
    #pragma unroll
    for (int i = 0; i < 4; ++i) {
      const int hr = (q << 2) + i;
      const float x = fmaxf((acc2[nt][i] - mu[i]) * rstd[i] * gv + bv, 0.f);
      *(unsigned short*)((char*)smem + hr * 512 + ((hc * 2) ^ ((hr & 7) << 4))) = f2b(x);
    }
  }
  __syncthreads();

  // GEMM3 + residual
  f32x4 acc3[2];
  acc3[0] = f32x4{0.f, 0.f, 0.f, 0.f};
  acc3[1] = f32x4{0.f, 0.f, 0.f, 0.f};
  for (int ks = 0; ks < 8; ++ks) {
    bf16x8 a = *(const bf16x8*)((const char*)smem + r * 512 + (((ks << 6) | (q << 4)) ^ swz));
    #pragma unroll
    for (int nt = 0; nt < 2; ++nt) {
      bf16x8 b = *(const bf16x8*)(W3 + ((((ww << 1) + nt) << 3) + ks) * 512 + (l << 3));
      acc3[nt] = MFMA(a, b, acc3[nt]);
    }
  }
  float y_loc[4][2];
  #pragma unroll
  for (int nt = 0; nt < 2; ++nt) {
    const float bias3 = b3[c0 + (nt << 4) + r];
    #pragma unroll
    for (int i = 0; i < 4; ++i) {
      const int nrow = r0 + (q << 2) + i;
      const int col = c0 + (nt << 4) + r;
      const float y = acc3[nt][i] + bias3 + nf[nrow * 256 + col];
      nf[nrow * 256 + col] = y;
      y_loc[i][nt] = y;
    }
  }
  __syncthreads();
  #pragma unroll
  for (int i = 0; i < 4; ++i) {
    const int hr = (q << 2) + i;
    const int hswz2 = (hr & 7) << 4;
    #pragma unroll
    for (int nt = 0; nt < 2; ++nt) {
      const int hc = c0 + (nt << 4) + r;
      *(unsigned short*)((char*)smem + hr * 512 + ((hc * 2) ^ hswz2)) = f2b(y_loc[i][nt]);
    }
  }
  __syncthreads();

  // P0 = y @ We1_top + e_b1
  f32x4 acc4[2];
  acc4[0] = f32x4{0.f, 0.f, 0.f, 0.f};
  acc4[1] = f32x4{0.f, 0.f, 0.f, 0.f};
  for (int ks = 0; ks < 8; ++ks) {
    bf16x8 a = *(const bf16x8*)((const char*)smem + r * 512 + (((ks << 6) | (q << 4)) ^ swz));
    #pragma unroll
    for (int nt = 0; nt < 2; ++nt) {
      bf16x8 b = *(const bf16x8*)(We1 + ((((ww << 1) + nt) << 4) + ks) * 512 + (l << 3));
      acc4[nt] = MFMA(a, b, acc4[nt]);
    }
  }
  #pragma unroll
  for (int nt = 0; nt < 2; ++nt) {
    const int col = c0 + (nt << 4) + r;
    const float bv = e_b1[col];
    #pragma unroll
    for (int i = 0; i < 4; ++i)
      P0out[(r0 + (q << 2) + i) * 256 + col] = f2b(acc4[nt][i] + bv);
  }

  if (Pp0out != nullptr) {
    f32x4 acc5[2];
    acc5[0] = f32x4{0.f, 0.f, 0.f, 0.f};
    acc5[1] = f32x4{0.f, 0.f, 0.f, 0.f};
    for (int ks = 0; ks < 8; ++ks) {
      bf16x8 a = *(const bf16x8*)((const char*)smem + r * 512 + (((ks << 6) | (q << 4)) ^ swz));
      #pragma unroll
      for (int nt = 0; nt < 2; ++nt) {
        bf16x8 b = *(const bf16x8*)(Wp1 + ((((ww << 1) + nt) << 4) + ks) * 512 + (l << 3));
        acc5[nt] = MFMA(a, b, acc5[nt]);
      }
    }
    #pragma unroll
    for (int nt = 0; nt < 2; ++nt) {
      const int col = c0 + (nt << 4) + r;
      const float bv = p_b1[col];
      #pragma unroll
      for (int i = 0; i < 4; ++i)
        Pp0out[(r0 + (q << 2) + i) * 256 + col] = f2b(acc5[nt][i] + bv);
    }
  }
}

// ---------------- edge predictor: sorted-order gather+add+relu+dot+sigmoid ----------------
__global__ __launch_bounds__(256, 4) void pred_kernel(
    const unsigned short* __restrict__ Pp0, const unsigned short* __restrict__ Pp1,
    const int* __restrict__ rowi, const int* __restrict__ coli,
    const int* __restrict__ perm,
    const float* __restrict__ w2, const float* __restrict__ b2,
    float* __restrict__ out)
{
  const int g = (int)blockIdx.x * 256 + (int)threadIdx.x;
  const int e = perm[g];
  const int prow = rowi[e] * 256, pcol = coli[e] * 256;
  float acc = 0.f;
  #pragma unroll 4
  for (int j = 0; j < 32; ++j) {
    const bf16x8 u = *(const bf16x8*)(Pp0 + prow + (j << 3));
    const bf16x8 v = *(const bf16x8*)(Pp1 + pcol + (j << 3));
    #pragma unroll
    for (int k = 0; k < 8; ++k)
      acc += fmaxf(b2f(u[k]) + b2f(v[k]), 0.f) * w2[(j << 3) + k];
  }
  out[e] = 1.f / (1.f + expf(-(acc + b2[0])));
}

// ---------------- launch ----------------
extern "C" void kernel_launch(void* const* d_in, const int* in_sizes, int n_in,
                              void* d_out, int out_size, void* d_ws, size_t ws_size,
                              hipStream_t stream) {
  const float* node0 = (const float*)d_in[0];
  const float* node1 = (const float*)d_in[1];
  const int* rowi = (const int*)d_in[2];
  const int* coli = (const int*)d_in[3];
  const float* e_w1 = (const float*)d_in[4];
  const float* e_b1 = (const float*)d_in[5];
  const float* e_w2 = (const float*)d_in[6];
  const float* e_b2 = (const float*)d_in[7];
  const float* e_g  = (const float*)d_in[8];
  const float* e_be = (const float*)d_in[9];
  const float* e_w3 = (const float*)d_in[10];
  const float* e_b3 = (const float*)d_in[11];
  const float* n_w1 = (const float*)d_in[12];
  const float* n_b1 = (const float*)d_in[13];
  const float* n_w2 = (const float*)d_in[14];
  const float* n_b2 = (const float*)d_in[15];
  const float* n_g  = (const float*)d_in[16];
  const float* n_be = (const float*)d_in[17];
  const float* n_w3 = (const float*)d_in[18];
  const float* n_b3 = (const float*)d_in[19];
  const float* p_w1 = (const float*)d_in[20];
  const float* p_b1 = (const float*)d_in[21];
  const float* p_w2 = (const float*)d_in[22];
  const float* p_b2 = (const float*)d_in[23];

  char* ws = (char*)d_ws;
  unsigned short* WTe1 = (unsigned short*)(ws + 0);
  unsigned short* WTe2 = (unsigned short*)(ws + 262144);
  unsigned short* WTe3 = (unsigned short*)(ws + 393216);
  unsigned short* WTn1 = (unsigned short*)(ws + 524288);
  unsigned short* WTn2 = (unsigned short*)(ws + 786432);
  unsigned short* WTn3 = (unsigned short*)(ws + 917504);
  unsigned short* WTp1 = (unsigned short*)(ws + 1048576);
  unsigned short* n1b  = (unsigned short*)(ws + 1310720);
  unsigned short* n0b  = (unsigned short*)(ws + 3407872);
  unsigned short* P0b  = (unsigned short*)(ws + 5505024);
  unsigned short* P1b  = (unsigned short*)(ws + 7602176);
  unsigned short* Pp0b = (unsigned short*)(ws + 9699328);
  unsigned short* Pp1b = (unsigned short*)(ws + 11796480);
  float* n0f  = (float*)(ws + 13893632);
  float* agg  = (float*)(ws + 18087936);     // S: segment sums of H2
  int* perm   = (int*)(ws + 22282240);
  int* posb   = (int*)(ws + 22806528);
  int* counts = (int*)(ws + 22822912);

  hipMemsetAsync(counts, 0, 4096 * 4, stream);
  hipMemsetAsync(agg, 0, (size_t)NN0 * 256 * 4, stream);
  prep_kernel<<<6656, 256, 0, stream>>>(e_w1, e_w2, e_w3, n_w1, n_w2, n_w3, p_w1,
                                        WTe1, WTe2, WTe3, WTn1, WTn2, WTn3, WTp1,
                                        node0, node1, n0b, n0f, n1b, rowi, counts);
  scan_kernel<<<1, 256, 0, stream>>>(counts, posb);
  fill_kernel<<<512, 256, 0, stream>>>(rowi, posb, perm);

  pre_gemm_kernel<<<384, 256, 0, stream>>>(n0b, n1b, WTe1, WTp1, e_b1, P0b, P1b, Pp1b);

  for (int it = 0; it < NMP; ++it) {
    edge_mlp_kernel<<<NEDGE / 64, 256, 0, stream>>>(P0b, P1b, rowi, coli, perm,
        WTe2, e_b2, e_g, e_be, agg);
    node_mlp_kernel<<<NN0 / 16, 512, 0, stream>>>(n0f, agg, counts,
        WTn1, n_b1, WTn2, n_b2, n_g, n_be, WTn3, n_b3,
        WTe3, e_b3, WTe1, e_b1, WTp1, p_b1, P0b, (it == NMP - 1) ? Pp0b : nullptr);
  }
  pred_kernel<<<NEDGE / 256, 256, 0, stream>>>(Pp0b, Pp1b, rowi, coli, perm,
      p_w2, p_b2, (float*)d_out);
}